// Round 11
// baseline (621.540 us; speedup 1.0000x reference)
//
#include <hip/hip_runtime.h>
#include <stdint.h>

#define Hn 512
#define Dn 128
#define Nn 64
#define Tn 512
#define NT (Nn*Tn)   // 32768

typedef unsigned int uint;
typedef unsigned short ushort;
typedef unsigned long long u64;

typedef __attribute__((ext_vector_type(4))) float f32x4;
typedef __attribute__((ext_vector_type(8))) int i32x8;
typedef __attribute__((ext_vector_type(8))) short short8;   // 8 bf16 (4 VGPRs)

// lgkm-only barrier: orders all LDS traffic across the WG without draining vmcnt,
// so global prefetch loads stay in flight across barriers.
#define WG_BARRIER() asm volatile("s_waitcnt lgkmcnt(0)\n\ts_barrier" ::: "memory")

// 3-ary max helper (compiles to v_max3_f32)
__device__ inline float max3f(float a, float b, float c) { return fmaxf(fmaxf(a, b), c); }

// ---------- ws layout (bytes) ----------
// emitb : 0x0000000  NT*Hn*2  = 32 MB  (exp(emit-rowmax)*rcsg, bf16, NATURAL col order)
// rm    : 0x2000000  NT*4     = 128 KB
// wmatb : 0x2020000  Hn*Dn*2  = 128 KB (bf16 logit weights)
// bias  : 0x2060000  Hn*4     = 2 KB
// rcsg  : 0x2062000  Hn*4     (colmax/448)
// px0s  : 0x2063000  Hn*4     (px[0][j]*cs[j], NATURAL order)
// pq    : 0x2070000  256 KB   (P fp8 e4m3, K=128 MFMA A-frags, sigma-permuted byte order)

__device__ inline float bf2f(ushort u) { union { uint i; float f; } v; v.i = uint(u) << 16; return v.f; }
__device__ inline float ubits(uint u) { union { uint i; float f; } v; v.i = u; return v.f; }
__device__ inline ushort f2bf(float f) {
  union { uint i; float f; } v; v.f = f;
  uint u = v.i;
  uint r = (u + 0x7FFFu + ((u >> 16) & 1u)) >> 16;
  return ushort(r);
}
// e4m3fn decode (non-negative only); finale only
__device__ inline float fp8val(uint b) {
  uint e = (b >> 3) & 15u, m = b & 7u;
  return e ? ldexpf((float)(8u + m), (int)e - 10) : ldexpf((float)m, -9);
}
// pack 8 floats to 8 e4m3 bytes; the (position -> k) convention is defined by k_preppq's
// sigma gather, applied identically to A and B so HW pairing cancels.
__device__ inline u64 pack8fp8(const float* v, float qs) {
  int lo = 0, hi = 0;
  lo = __builtin_amdgcn_cvt_pk_fp8_f32(v[0] * qs, v[1] * qs, lo, false);
  lo = __builtin_amdgcn_cvt_pk_fp8_f32(v[2] * qs, v[3] * qs, lo, true);
  hi = __builtin_amdgcn_cvt_pk_fp8_f32(v[4] * qs, v[5] * qs, hi, false);
  hi = __builtin_amdgcn_cvt_pk_fp8_f32(v[6] * qs, v[7] * qs, hi, true);
  return (u64)(uint)lo | ((u64)(uint)hi << 32);
}

// FUSED k_prep + colmax + P-quantize. Blocks 0..255: prep (2 rows of py each).
// Blocks 256..287: quantize m-tile (ntg = b-256) into sigma-permuted A-frag order:
// byte (qa, jj) of block kb <-> k = kb*128 + (qa>>1)*64 + ((jj>>2)&3)*16 + (qa&1)*8 + (jj>>4)*4 + (jj&3)
__global__ __launch_bounds__(256) void k_preppq(
    const float* __restrict__ py, const float* __restrict__ px,
    ushort* __restrict__ wmatb, float* __restrict__ bias,
    float* __restrict__ rcsg, float* __restrict__ px0s, u64* __restrict__ pq) {
  __shared__ float ksl[512][17];   // 34 KB, padded stride
  __shared__ float pm[16][17];
  __shared__ float csL[16];
  __shared__ float s2[4];
  int b = blockIdx.x;
  int t = threadIdx.x;
  if (b < 256) {
    // ---- prep: rows 2b, 2b+1 of py ----
    int h = 2 * b + (t >> 7), d = t & 127;
    float p = py[h * Dn + d];
    float lp = logf(p), l1 = log1pf(-p);
    wmatb[h * Dn + d] = f2bf(lp - l1);   // logit, bf16 (A operand is exact 0/1)
    float v = l1;
    for (int o = 1; o < 64; o <<= 1) v += __shfl_xor(v, o, 64);
    if ((t & 63) == 0) s2[t >> 6] = v;
    __syncthreads();
    if ((t & 127) == 0) bias[h] = s2[(t >> 7) * 2] + s2[(t >> 7) * 2 + 1];
    return;
  }
  int ntg = b - 256;               // global m-tile 0..31
  for (int i = 0; i < 8; i++) {
    int q = i * 256 + t;           // float4 id over 512x16
    int row = q >> 2, c4 = q & 3;
    float4 v = *(const float4*)(px + (size_t)row * Hn + ntg * 16 + c4 * 4);
    ksl[row][c4 * 4 + 0] = v.x; ksl[row][c4 * 4 + 1] = v.y;
    ksl[row][c4 * 4 + 2] = v.z; ksl[row][c4 * 4 + 3] = v.w;
  }
  __syncthreads();
  // col-max of the staged 512x16 slice
  {
    int c = t & 15, ch = t >> 4;   // 16 chunks x 32 rows
    float m = 0.f;
#pragma unroll
    for (int r = 0; r < 30; r += 3) m = max3f(m, fmaxf(ksl[ch * 32 + r][c], ksl[ch * 32 + r + 1][c]), ksl[ch * 32 + r + 2][c]);
    m = max3f(m, ksl[ch * 32 + 30][c], ksl[ch * 32 + 31][c]);
    pm[ch][c] = m;
  }
  __syncthreads();
  if (t < 16) {
    float m = pm[0][t];
#pragma unroll
    for (int i = 1; i < 15; i += 2) m = max3f(m, pm[i][t], pm[i + 1][t]);
    m = fmaxf(m, pm[15][t]);
    float c = 448.0f / m;
    csL[t] = c;
    rcsg[ntg * 16 + t] = m * (1.0f / 448.0f);
    px0s[ntg * 16 + t] = px[ntg * 16 + t] * c;   // row 0 of px, pre-scaled, NATURAL
  }
  __syncthreads();
  int kb = t >> 6, lane = t & 63, qa = lane >> 4, c15 = lane & 15;
  float csv = csL[c15];
  int kbase = kb * 128 + (qa >> 1) * 64 + (qa & 1) * 8;
  size_t base = ((size_t)(((ntg >> 2) * 16 + kb * 4 + (ntg & 3)) * 64 + lane)) * 4;
#pragma unroll
  for (int d = 0; d < 4; d++) {
    float vv[8];
#pragma unroll
    for (int bb = 0; bb < 8; bb++) {
      int jj = d * 8 + bb;
      int kk = kbase + (((jj >> 2) & 3) << 4) + ((jj >> 4) << 2) + (jj & 3);
      vv[bb] = ksl[kk][c15];
    }
    pq[base + d] = pack8fp8(vv, csv);
  }
}

// FUSED emit GEMM (bf16 MFMA) + rowmax + exp + rcsg-scale + NATURAL eb store + rm store.
// B staged in 4 chunks of 128 rows -> 56 KB LDS -> 2 WGs/CU. Natural store order:
// 16-lane-contiguous 2B runs coalesce in the TA (no column scatter).
__global__ __launch_bounds__(256, 2) void k_emit3(
    const float* __restrict__ A, const ushort* __restrict__ wmatb,
    const float* __restrict__ bias, const float* __restrict__ rcsg,
    ushort* __restrict__ eb, float* __restrict__ rm) {
  __shared__ ushort Bs[128][136];   // 34816 B (one 128-row chunk of wmatb)
  __shared__ ushort As[64][136];    // 17408 B
  __shared__ float biasL[512];      // 2 KB
  __shared__ float rcsL[512];       // 2 KB
  int t = threadIdx.x;
  int r0 = blockIdx.x * 64;
  // stage A: 64 rows x 128 f32 -> bf16 (values 0/1: exact)
  for (int i = 0; i < 8; i++) {
    int q = i * 256 + t, row = q >> 5, c4 = q & 31;
    float4 v = *(const float4*)(A + (size_t)(r0 + row) * Dn + c4 * 4);
    ushort4 u4 = {f2bf(v.x), f2bf(v.y), f2bf(v.z), f2bf(v.w)};
    *(ushort4*)&As[row][c4 * 4] = u4;
  }
  biasL[t] = bias[t]; biasL[t + 256] = bias[t + 256];
  rcsL[t] = rcsg[t];  rcsL[t + 256] = rcsg[t + 256];
  __syncthreads();

  const int w = t >> 6, lane = t & 63, l15 = lane & 15, g4 = lane >> 4;
  // A fragments: row = w*16 + l15, k = kt*32 + g4*8 .. +8
  short8 afr[4];
#pragma unroll
  for (int kt = 0; kt < 4; kt++)
    afr[kt] = *(const short8*)&As[w * 16 + l15][kt * 32 + g4 * 8];

  f32x4 acc[32];
  for (int cc = 0; cc < 4; cc++) {
    __syncthreads();   // Bs free for overwrite
    for (int i = 0; i < 8; i++) {
      int q = i * 256 + t, row = q >> 4, c = q & 15;
      *(uint4*)&Bs[row][c * 8] = *(const uint4*)(wmatb + (cc * 128 + row) * 128 + c * 8);
    }
    __syncthreads();   // Bs staged
#pragma unroll
    for (int n8 = 0; n8 < 8; n8++) {
      int nt = cc * 8 + n8;
      f32x4 a = {0.f, 0.f, 0.f, 0.f};
#pragma unroll
      for (int kt = 0; kt < 4; kt++) {
        short8 bfr = *(const short8*)&Bs[n8 * 16 + l15][kt * 32 + g4 * 8];
        a = __builtin_amdgcn_mfma_f32_16x16x32_bf16(afr[kt], bfr, a, 0, 0, 0);
      }
      acc[nt] = a;
    }
  }
  // bias + per-row max (row = w*16 + g4*4 + r, col = nt*16 + l15)
  float mrow[4] = {-1e30f, -1e30f, -1e30f, -1e30f};
#pragma unroll
  for (int nt = 0; nt < 32; nt++) {
    float bv = biasL[nt * 16 + l15];
#pragma unroll
    for (int r = 0; r < 4; r++) {
      float v = acc[nt][r] + bv;
      acc[nt][r] = v;
      mrow[r] = fmaxf(mrow[r], v);
    }
  }
#pragma unroll
  for (int o = 1; o < 16; o <<= 1) {
    mrow[0] = fmaxf(mrow[0], __shfl_xor(mrow[0], o, 64));
    mrow[1] = fmaxf(mrow[1], __shfl_xor(mrow[1], o, 64));
    mrow[2] = fmaxf(mrow[2], __shfl_xor(mrow[2], o, 64));
    mrow[3] = fmaxf(mrow[3], __shfl_xor(mrow[3], o, 64));
  }
  if (l15 == 0) {
#pragma unroll
    for (int r = 0; r < 4; r++) rm[(size_t)(r0 + w * 16 + g4 * 4 + r)] = mrow[r];
  }
  // exp + scale + NATURAL store (col = nt*16 + l15): 16-lane-contiguous runs
  ushort* ebase = eb + (size_t)(r0 + w * 16 + g4 * 4) * Hn;
#pragma unroll
  for (int nt = 0; nt < 32; nt++) {
    float rc = rcsL[nt * 16 + l15];
#pragma unroll
    for (int r = 0; r < 4; r++) {
      float e = __expf(acc[nt][r] - mrow[r]) * rc;
      ebase[(size_t)r * Hn + nt * 16 + l15] = f2bf(e);
    }
  }
}

// 4 WGs x 512 threads (8 waves). D = P(A) x alpha(B), sigma-permuted k-order.
// Lane (qg,l15) of wave w owns seq l15, cols {w*64 + mt*16 + qg*4 + r} — and packs
// those SAME 16 registers directly into its 16B BfI slot (no ut array, no transpose).
// BfI layout [slot16B][seq]: quantize write and MFMA read are both contiguous
// per-wave patterns (conflict-free). B-frag ds_reads land DIRECTLY in i32x8 tuples.
__global__ __launch_bounds__(512, 2) void k_rec11(
    const ushort* __restrict__ eb, const float* __restrict__ rm,
    const u64* __restrict__ pq, const float* __restrict__ px0s,
    const int* __restrict__ lens, float* __restrict__ outp) {
  const int grp = blockIdx.x;        // 0..3
  const int t = threadIdx.x;         // 0..511
  const int w = t >> 6;              // wave 0..7
  const int lane = t & 63, qg = lane >> 4, l15 = lane & 15;

  __shared__ uint4 BfI[32][16];      // alpha fp8 image [16B-slot][seq] (8 KB)
  __shared__ float sredM[16][12];    // per-seq per-wave partial max
  __shared__ float rmsL[16];
  __shared__ int lenl[16];

  // ---- persistent P fragments (A operand): wave w -> m-tiles 4w..4w+3 ----
  i32x8 PRv[16];
  {
    const uint4* pqv = (const uint4*)pq;
#pragma unroll
    for (int f = 0; f < 16; f++) {
      *(uint4*)&PRv[f]       = pqv[((size_t)(w * 16 + f) * 64 + lane) * 2 + 0];
      *(((uint4*)&PRv[f])+1) = pqv[((size_t)(w * 16 + f) * 64 + lane) * 2 + 1];
    }
  }

  if (t < 16) lenl[t] = lens[grp * 16 + t];
  const size_t seqstride = (size_t)Tn * Hn;
  // lane's 16 cols: w*64 + mt*16 + qg*4 + r -> 4 x u64 loads at base + mt*16
  const ushort* myrow = eb + (size_t)(grp * 16 + l15) * seqstride + w * 64 + qg * 4;
  uint4* myslot = &BfI[w * 4 + qg][l15];

  float4 uv0, uv1, uv2, uv3;
  // ---- init: uv_mt[r] = px0s[col] * e'[col], natural order ----
  {
    u64 e0 = *(const u64*)(myrow + 0);
    u64 e1 = *(const u64*)(myrow + 16);
    u64 e2 = *(const u64*)(myrow + 32);
    u64 e3 = *(const u64*)(myrow + 48);
    float4 p0 = *(const float4*)(px0s + w * 64 + 0 * 16 + qg * 4);
    float4 p1 = *(const float4*)(px0s + w * 64 + 1 * 16 + qg * 4);
    float4 p2 = *(const float4*)(px0s + w * 64 + 2 * 16 + qg * 4);
    float4 p3 = *(const float4*)(px0s + w * 64 + 3 * 16 + qg * 4);
    uint lo, hi;
    lo = (uint)e0; hi = (uint)(e0 >> 32);
    uv0.x = p0.x * ubits(lo << 16); uv0.y = p0.y * ubits(lo & 0xffff0000u);
    uv0.z = p0.z * ubits(hi << 16); uv0.w = p0.w * ubits(hi & 0xffff0000u);
    lo = (uint)e1; hi = (uint)(e1 >> 32);
    uv1.x = p1.x * ubits(lo << 16); uv1.y = p1.y * ubits(lo & 0xffff0000u);
    uv1.z = p1.z * ubits(hi << 16); uv1.w = p1.w * ubits(hi & 0xffff0000u);
    lo = (uint)e2; hi = (uint)(e2 >> 32);
    uv2.x = p2.x * ubits(lo << 16); uv2.y = p2.y * ubits(lo & 0xffff0000u);
    uv2.z = p2.z * ubits(hi << 16); uv2.w = p2.w * ubits(hi & 0xffff0000u);
    lo = (uint)e3; hi = (uint)(e3 >> 32);
    uv3.x = p3.x * ubits(lo << 16); uv3.y = p3.y * ubits(lo & 0xffff0000u);
    uv3.z = p3.z * ubits(hi << 16); uv3.w = p3.w * ubits(hi & 0xffff0000u);
    float ma = max3f(max3f(uv0.x, uv0.y, uv0.z), max3f(uv0.w, uv1.x, uv1.y),
                     max3f(uv1.z, uv1.w, uv2.x));
    float mb = max3f(max3f(uv2.y, uv2.z, uv2.w), max3f(uv3.x, uv3.y, uv3.z), uv3.w);
    float mxv = fmaxf(ma, mb);
    mxv = fmaxf(mxv, __shfl_xor(mxv, 16, 64));
    mxv = fmaxf(mxv, __shfl_xor(mxv, 32, 64));
    if (qg == 0) sredM[l15][w] = mxv;
  }
  WG_BARRIER();
  const int t_end = lenl[15];
  const int lenq = lenl[l15];
  float L2acc;
  u64 myf0, myf1;

  // ---- step-0 quantize: pack OWN 16 registers into own slot ----
  {
    float4 g0 = *(const float4*)&sredM[l15][0];
    float4 g1 = *(const float4*)&sredM[l15][4];
    float gm = fmaxf(max3f(max3f(g0.x, g0.y, g0.z), max3f(g0.w, g1.x, g1.y), g1.z), g1.w);
    L2acc = __log2f(gm);
    float qs = 448.0f * __builtin_amdgcn_rcpf(gm);
    float v0[8] = {uv0.x, uv0.y, uv0.z, uv0.w, uv1.x, uv1.y, uv1.z, uv1.w};
    float v1[8] = {uv2.x, uv2.y, uv2.z, uv2.w, uv3.x, uv3.y, uv3.z, uv3.w};
    myf0 = pack8fp8(v0, qs);
    myf1 = pack8fp8(v1, qs);
    *myslot = (uint4){(uint)myf0, (uint)(myf0 >> 32), (uint)myf1, (uint)(myf1 >> 32)};
  }

  // ---- emit prefetch: 4 x u64 per lane ----
  const ushort* epp = myrow + Hn;
  u64 bp0 = *(const u64*)(epp + 0),  bp1 = *(const u64*)(epp + 16);
  u64 bp2 = *(const u64*)(epp + 32), bp3 = *(const u64*)(epp + 48);
  epp += Hn;

  // ---- recursion: 2 lgkm-only barriers/step ----
  for (int ts = 1; ts < t_end; ts++) {
    WG_BARRIER();  // BAR0: BfI published

    // B-frags: ds_read_b128 pairs land directly in i32x8 tuple halves (no marshaling)
    i32x8 bfv[4];
#pragma unroll
    for (int kb = 0; kb < 4; kb++) {
      *(uint4*)&bfv[kb]       = BfI[kb * 8 + qg * 2 + 0][l15];
      *(((uint4*)&bfv[kb])+1) = BfI[kb * 8 + qg * 2 + 1][l15];
    }

    // MFMA: 4 k-blocks (K=128) x 4 m-tiles; A=P regs, B=alpha LDS
    f32x4 ac0 = {0.f, 0.f, 0.f, 0.f}, ac1 = {0.f, 0.f, 0.f, 0.f};
    f32x4 ac2 = {0.f, 0.f, 0.f, 0.f}, ac3 = {0.f, 0.f, 0.f, 0.f};
    __builtin_amdgcn_s_setprio(1);
#pragma unroll
    for (int kb = 0; kb < 4; kb++) {
      ac0 = __builtin_amdgcn_mfma_scale_f32_16x16x128_f8f6f4(
          PRv[kb * 4 + 0], bfv[kb], ac0, 0, 0, 0, 0x7F7F7F7F, 0, 0x7F7F7F7F);
      ac1 = __builtin_amdgcn_mfma_scale_f32_16x16x128_f8f6f4(
          PRv[kb * 4 + 1], bfv[kb], ac1, 0, 0, 0, 0x7F7F7F7F, 0, 0x7F7F7F7F);
      ac2 = __builtin_amdgcn_mfma_scale_f32_16x16x128_f8f6f4(
          PRv[kb * 4 + 2], bfv[kb], ac2, 0, 0, 0, 0x7F7F7F7F, 0, 0x7F7F7F7F);
      ac3 = __builtin_amdgcn_mfma_scale_f32_16x16x128_f8f6f4(
          PRv[kb * 4 + 3], bfv[kb], ac3, 0, 0, 0, 0x7F7F7F7F, 0, 0x7F7F7F7F);
    }
    __builtin_amdgcn_s_setprio(0);

    // prefetch emit(ts+1) AFTER the MFMA issue (off the pre-MFMA critical path)
    u64 bq0 = *(const u64*)(epp + 0),  bq1 = *(const u64*)(epp + 16);
    u64 bq2 = *(const u64*)(epp + 32), bq3 = *(const u64*)(epp + 48);
    epp += Hn;

    // epilogue: u = acc * e' entirely in registers; per-seq max via max3 + 2 shfl
    {
      uint lo, hi;
      lo = (uint)bp0; hi = (uint)(bp0 >> 32);
      uv0.x = ac0[0] * ubits(lo << 16); uv0.y = ac0[1] * ubits(lo & 0xffff0000u);
      uv0.z = ac0[2] * ubits(hi << 16); uv0.w = ac0[3] * ubits(hi & 0xffff0000u);
      lo = (uint)bp1; hi = (uint)(bp1 >> 32);
      uv1.x = ac1[0] * ubits(lo << 16); uv1.y = ac1[1] * ubits(lo & 0xffff0000u);
      uv1.z = ac1[2] * ubits(hi << 16); uv1.w = ac1[3] * ubits(hi & 0xffff0000u);
      lo = (uint)bp2; hi = (uint)(bp2 >> 32);
      uv2.x = ac2[0] * ubits(lo << 16); uv2.y = ac2[1] * ubits(lo & 0xffff0000u);
      uv2.z = ac2[2] * ubits(hi << 16); uv2.w = ac2[3] * ubits(hi & 0xffff0000u);
      lo = (uint)bp3; hi = (uint)(bp3 >> 32);
      uv3.x = ac3[0] * ubits(lo << 16); uv3.y = ac3[1] * ubits(lo & 0xffff0000u);
      uv3.z = ac3[2] * ubits(hi << 16); uv3.w = ac3[3] * ubits(hi & 0xffff0000u);
      float ma = max3f(max3f(uv0.x, uv0.y, uv0.z), max3f(uv0.w, uv1.x, uv1.y),
                       max3f(uv1.z, uv1.w, uv2.x));
      float mb = max3f(max3f(uv2.y, uv2.z, uv2.w), max3f(uv3.x, uv3.y, uv3.z), uv3.w);
      float mxv = fmaxf(ma, mb);
      mxv = fmaxf(mxv, __shfl_xor(mxv, 16, 64));
      mxv = fmaxf(mxv, __shfl_xor(mxv, 32, 64));
      if (qg == 0) sredM[l15][w] = mxv;
    }
    WG_BARRIER();  // BAR1: sredM published (only cross-wave dependency)

    // quantize: pack OWN registers, write own slot (conflict-free contiguous write)
    if (ts < lenq) {
      float4 g0 = *(const float4*)&sredM[l15][0];
      float4 g1 = *(const float4*)&sredM[l15][4];
      float gm = fmaxf(max3f(max3f(g0.x, g0.y, g0.z), max3f(g0.w, g1.x, g1.y), g1.z), g1.w);
      L2acc += __log2f(gm);
      float qs = 448.0f * __builtin_amdgcn_rcpf(gm);
      float v0[8] = {uv0.x, uv0.y, uv0.z, uv0.w, uv1.x, uv1.y, uv1.z, uv1.w};
      float v1[8] = {uv2.x, uv2.y, uv2.z, uv2.w, uv3.x, uv3.y, uv3.z, uv3.w};
      myf0 = pack8fp8(v0, qs);
      myf1 = pack8fp8(v1, qs);
      *myslot = (uint4){(uint)myf0, (uint)(myf0 >> 32), (uint)myf1, (uint)(myf1 >> 32)};
    }
    bp0 = bq0; bp1 = bq1; bp2 = bq2; bp3 = bq3;
  }

  // ---- finale ----
  WG_BARRIER();
  {
    float ps = 0.f;
#pragma unroll
    for (int j = 0; j < 8; j++) {
      ps += fp8val((uint)(myf0 >> (8 * j)) & 0xffu);
      ps += fp8val((uint)(myf1 >> (8 * j)) & 0xffu);
    }
    ps += __shfl_xor(ps, 16, 64);
    ps += __shfl_xor(ps, 32, 64);
    if (qg == 0) sredM[l15][w] = ps;  // partial sum over this wave's k-window, seq l15
  }
  // rm sums: wave w handles seqs 2w (lanes 0..31), 2w+1 (lanes 32..63)
  {
    int sq = 2 * w + (lane >> 5), tl = lane & 31;
    const float* rp = rm + (size_t)(grp * 16 + sq) * Tn;
    int ls = lenl[sq];
    float rs = 0.f;
#pragma unroll
    for (int k = 0; k < 16; k++) {
      int idx = tl + 32 * k;
      float v = rp[idx];
      rs += (idx < ls) ? v : 0.f;
    }
#pragma unroll
    for (int o = 1; o < 32; o <<= 1) rs += __shfl_xor(rs, o, 64);
    if ((lane & 31) == 0) rmsL[sq] = rs;
  }
  __syncthreads();
  if (t < 16) {  // wave 0, qg 0, l15 = t: holds L2acc/lenq for seq t
    float4 s0 = *(const float4*)&sredM[t][0];
    float4 s1 = *(const float4*)&sredM[t][4];
    float Ss = (s0.x + s0.y) + (s0.z + s0.w) + (s1.x + s1.y) + (s1.z + s1.w);
    outp[grp * 16 + t] = 0.6931471805599453f * L2acc - (float)lenq * 6.104793232414985f
                         + logf(Ss) + rmsL[t];
  }
}

extern "C" void kernel_launch(void* const* d_in, const int* in_sizes, int n_in,
                              void* d_out, int out_size, void* d_ws, size_t ws_size,
                              hipStream_t stream) {
  const float* seq = (const float*)d_in[0];
  const int* lens = (const int*)d_in[1];
  const float* px = (const float*)d_in[2];
  const float* py = (const float*)d_in[3];
  char* ws = (char*)d_ws;
  ushort* emitb = (ushort*)(ws + 0x0000000);
  float* rm     = (float*)(ws + 0x2000000);
  ushort* wmatb = (ushort*)(ws + 0x2020000);
  float* bias   = (float*)(ws + 0x2060000);
  float* rcsg   = (float*)(ws + 0x2062000);
  float* px0s   = (float*)(ws + 0x2063000);
  u64* pq       = (u64*)(ws + 0x2070000);
  float* outp   = (float*)d_out;

  hipLaunchKernelGGL(k_preppq, dim3(288), dim3(256), 0, stream, py, px, wmatb, bias, rcsg, px0s, pq);
  hipLaunchKernelGGL(k_emit3, dim3(NT / 64), dim3(256), 0, stream, seq, wmatb, bias, rcsg, emitb, rm);
  hipLaunchKernelGGL(k_rec11, dim3(4), dim3(512), 0, stream, emitb, rm, pq, px0s, lens, outp);
}

// Round 12
// 575.805 us; speedup vs baseline: 1.0794x; 1.0794x over previous
//
#include <hip/hip_runtime.h>
#include <stdint.h>

#define Hn 512
#define Dn 128
#define Nn 64
#define Tn 512
#define NT (Nn*Tn)   // 32768

typedef unsigned int uint;
typedef unsigned short ushort;
typedef unsigned long long u64;

typedef __attribute__((ext_vector_type(4))) float f32x4;
typedef __attribute__((ext_vector_type(8))) int i32x8;
typedef __attribute__((ext_vector_type(8))) short short8;   // 8 bf16 (4 VGPRs)

// lgkm-only barrier: orders all LDS traffic across the WG without draining vmcnt,
// so global prefetch loads stay in flight across barriers.
#define WG_BARRIER() asm volatile("s_waitcnt lgkmcnt(0)\n\ts_barrier" ::: "memory")

// 3-ary max helper (compiles to v_max3_f32)
__device__ inline float max3f(float a, float b, float c) { return fmaxf(fmaxf(a, b), c); }

// ---------- ws layout (bytes) ----------
// emitb : 0x0000000  NT*Hn*2  = 32 MB  (exp(emit-rowmax)*rcsg, bf16; cols PERMUTED:
//                    each k_rec lane's 16 values are one contiguous 32B run)
// rm    : 0x2000000  NT*4     = 128 KB
// wmatb : 0x2020000  Hn*Dn*2  = 128 KB (bf16 logit weights)
// bias  : 0x2060000  Hn*4     = 2 KB
// rcsg  : 0x2062000  Hn*4     (colmax/448)
// px0sp : 0x2063000  Hn*4     (px[0][j]*cs[j], stored PERMUTED like emitb)
// pq    : 0x2070000  256 KB   (P fp8 e4m3, K=128 MFMA A-frags, sigma-permuted byte order)

__device__ inline float bf2f(ushort u) { union { uint i; float f; } v; v.i = uint(u) << 16; return v.f; }
__device__ inline float ubits(uint u) { union { uint i; float f; } v; v.i = u; return v.f; }
__device__ inline ushort f2bf(float f) {
  union { uint i; float f; } v; v.f = f;
  uint u = v.i;
  uint r = (u + 0x7FFFu + ((u >> 16) & 1u)) >> 16;
  return ushort(r);
}
// e4m3fn decode (non-negative only); finale only
__device__ inline float fp8val(uint b) {
  uint e = (b >> 3) & 15u, m = b & 7u;
  return e ? ldexpf((float)(8u + m), (int)e - 10) : ldexpf((float)m, -9);
}
// pack 8 floats to 8 e4m3 bytes; the (position -> k) convention is defined by k_preppq's
// sigma gather, applied identically to A and B so HW pairing cancels.
__device__ inline u64 pack8fp8(const float* v, float qs) {
  int lo = 0, hi = 0;
  lo = __builtin_amdgcn_cvt_pk_fp8_f32(v[0] * qs, v[1] * qs, lo, false);
  lo = __builtin_amdgcn_cvt_pk_fp8_f32(v[2] * qs, v[3] * qs, lo, true);
  hi = __builtin_amdgcn_cvt_pk_fp8_f32(v[4] * qs, v[5] * qs, hi, false);
  hi = __builtin_amdgcn_cvt_pk_fp8_f32(v[6] * qs, v[7] * qs, hi, true);
  return (u64)(uint)lo | ((u64)(uint)hi << 32);
}
// col permutation for emitb/px0sp: swap (mt, qg) 2-bit fields within each 64-block
__device__ inline int permcol(int c) {
  return (c & ~63) | ((c & 12) << 2) | ((c & 48) >> 2) | (c & 3);
}

// FUSED k_prep + colmax + P-quantize. Blocks 0..255: prep (2 rows of py each).
// Blocks 256..287: quantize m-tile (ntg = b-256) into sigma-permuted A-frag order:
// byte (qa, jj) of block kb <-> k = kb*128 + (qa>>1)*64 + ((jj>>2)&3)*16 + (qa&1)*8 + (jj>>4)*4 + (jj&3)
__global__ __launch_bounds__(256) void k_preppq(
    const float* __restrict__ py, const float* __restrict__ px,
    ushort* __restrict__ wmatb, float* __restrict__ bias,
    float* __restrict__ rcsg, float* __restrict__ px0sp, u64* __restrict__ pq) {
  __shared__ float ksl[512][17];   // 34 KB, padded stride
  __shared__ float pm[16][17];
  __shared__ float csL[16];
  __shared__ float s2[4];
  int b = blockIdx.x;
  int t = threadIdx.x;
  if (b < 256) {
    // ---- prep: rows 2b, 2b+1 of py ----
    int h = 2 * b + (t >> 7), d = t & 127;
    float p = py[h * Dn + d];
    float lp = logf(p), l1 = log1pf(-p);
    wmatb[h * Dn + d] = f2bf(lp - l1);   // logit, bf16 (A operand is exact 0/1)
    float v = l1;
    for (int o = 1; o < 64; o <<= 1) v += __shfl_xor(v, o, 64);
    if ((t & 63) == 0) s2[t >> 6] = v;
    __syncthreads();
    if ((t & 127) == 0) bias[h] = s2[(t >> 7) * 2] + s2[(t >> 7) * 2 + 1];
    return;
  }
  int ntg = b - 256;               // global m-tile 0..31
  for (int i = 0; i < 8; i++) {
    int q = i * 256 + t;           // float4 id over 512x16
    int row = q >> 2, c4 = q & 3;
    float4 v = *(const float4*)(px + (size_t)row * Hn + ntg * 16 + c4 * 4);
    ksl[row][c4 * 4 + 0] = v.x; ksl[row][c4 * 4 + 1] = v.y;
    ksl[row][c4 * 4 + 2] = v.z; ksl[row][c4 * 4 + 3] = v.w;
  }
  __syncthreads();
  // col-max of the staged 512x16 slice
  {
    int c = t & 15, ch = t >> 4;   // 16 chunks x 32 rows
    float m = 0.f;
#pragma unroll
    for (int r = 0; r < 30; r += 3) m = max3f(m, fmaxf(ksl[ch * 32 + r][c], ksl[ch * 32 + r + 1][c]), ksl[ch * 32 + r + 2][c]);
    m = max3f(m, ksl[ch * 32 + 30][c], ksl[ch * 32 + 31][c]);
    pm[ch][c] = m;
  }
  __syncthreads();
  if (t < 16) {
    float m = pm[0][t];
#pragma unroll
    for (int i = 1; i < 15; i += 2) m = max3f(m, pm[i][t], pm[i + 1][t]);
    m = fmaxf(m, pm[15][t]);
    float c = 448.0f / m;
    csL[t] = c;
    rcsg[ntg * 16 + t] = m * (1.0f / 448.0f);
    px0sp[permcol(ntg * 16 + t)] = px[ntg * 16 + t] * c;   // row 0 of px, pre-scaled
  }
  __syncthreads();
  int kb = t >> 6, lane = t & 63, qa = lane >> 4, c15 = lane & 15;
  float csv = csL[c15];
  int kbase = kb * 128 + (qa >> 1) * 64 + (qa & 1) * 8;
  size_t base = ((size_t)(((ntg >> 2) * 16 + kb * 4 + (ntg & 3)) * 64 + lane)) * 4;
#pragma unroll
  for (int d = 0; d < 4; d++) {
    float vv[8];
#pragma unroll
    for (int bb = 0; bb < 8; bb++) {
      int jj = d * 8 + bb;
      int kk = kbase + (((jj >> 2) & 3) << 4) + ((jj >> 4) << 2) + (jj & 3);
      vv[bb] = ksl[kk][c15];
    }
    pq[base + d] = pack8fp8(vv, csv);
  }
}

// FUSED emit GEMM (bf16 MFMA) + rowmax + exp + rcsg-scale + permuted eb store + rm store.
// B staged in 4 chunks of 128 rows -> 56 KB LDS -> 2 WGs/CU.
__global__ __launch_bounds__(256, 2) void k_emit3(
    const float* __restrict__ A, const ushort* __restrict__ wmatb,
    const float* __restrict__ bias, const float* __restrict__ rcsg,
    ushort* __restrict__ eb, float* __restrict__ rm) {
  __shared__ ushort Bs[128][136];   // 34816 B (one 128-row chunk of wmatb)
  __shared__ ushort As[64][136];    // 17408 B
  __shared__ float biasL[512];      // 2 KB
  __shared__ float rcsL[512];       // 2 KB
  int t = threadIdx.x;
  int r0 = blockIdx.x * 64;
  // stage A: 64 rows x 128 f32 -> bf16 (values 0/1: exact)
  for (int i = 0; i < 8; i++) {
    int q = i * 256 + t, row = q >> 5, c4 = q & 31;
    float4 v = *(const float4*)(A + (size_t)(r0 + row) * Dn + c4 * 4);
    ushort4 u4 = {f2bf(v.x), f2bf(v.y), f2bf(v.z), f2bf(v.w)};
    *(ushort4*)&As[row][c4 * 4] = u4;
  }
  biasL[t] = bias[t]; biasL[t + 256] = bias[t + 256];
  rcsL[t] = rcsg[t];  rcsL[t + 256] = rcsg[t + 256];
  __syncthreads();

  const int w = t >> 6, lane = t & 63, l15 = lane & 15, g4 = lane >> 4;
  // A fragments: row = w*16 + l15, k = kt*32 + g4*8 .. +8
  short8 afr[4];
#pragma unroll
  for (int kt = 0; kt < 4; kt++)
    afr[kt] = *(const short8*)&As[w * 16 + l15][kt * 32 + g4 * 8];

  f32x4 acc[32];
  for (int cc = 0; cc < 4; cc++) {
    __syncthreads();   // Bs free for overwrite
    for (int i = 0; i < 8; i++) {
      int q = i * 256 + t, row = q >> 4, c = q & 15;
      *(uint4*)&Bs[row][c * 8] = *(const uint4*)(wmatb + (cc * 128 + row) * 128 + c * 8);
    }
    __syncthreads();   // Bs staged
#pragma unroll
    for (int n8 = 0; n8 < 8; n8++) {
      int nt = cc * 8 + n8;
      f32x4 a = {0.f, 0.f, 0.f, 0.f};
#pragma unroll
      for (int kt = 0; kt < 4; kt++) {
        short8 bfr = *(const short8*)&Bs[n8 * 16 + l15][kt * 32 + g4 * 8];
        a = __builtin_amdgcn_mfma_f32_16x16x32_bf16(afr[kt], bfr, a, 0, 0, 0);
      }
      acc[nt] = a;
    }
  }
  // bias + per-row max (row = w*16 + g4*4 + r, col = nt*16 + l15)
  float mrow[4] = {-1e30f, -1e30f, -1e30f, -1e30f};
#pragma unroll
  for (int nt = 0; nt < 32; nt++) {
    float bv = biasL[nt * 16 + l15];
#pragma unroll
    for (int r = 0; r < 4; r++) {
      float v = acc[nt][r] + bv;
      acc[nt][r] = v;
      mrow[r] = fmaxf(mrow[r], v);
    }
  }
#pragma unroll
  for (int o = 1; o < 16; o <<= 1) {
    mrow[0] = fmaxf(mrow[0], __shfl_xor(mrow[0], o, 64));
    mrow[1] = fmaxf(mrow[1], __shfl_xor(mrow[1], o, 64));
    mrow[2] = fmaxf(mrow[2], __shfl_xor(mrow[2], o, 64));
    mrow[3] = fmaxf(mrow[3], __shfl_xor(mrow[3], o, 64));
  }
  if (l15 == 0) {
#pragma unroll
    for (int r = 0; r < 4; r++) rm[(size_t)(r0 + w * 16 + g4 * 4 + r)] = mrow[r];
  }
  // exp + scale + PERMUTED store
  ushort* ebase = eb + (size_t)(r0 + w * 16 + g4 * 4) * Hn;
#pragma unroll
  for (int nt = 0; nt < 32; nt++) {
    int colp = (nt >> 2) * 64 + (l15 >> 2) * 16 + (nt & 3) * 4 + (l15 & 3);
    float rc = rcsL[nt * 16 + l15];
#pragma unroll
    for (int r = 0; r < 4; r++) {
      float e = __expf(acc[nt][r] - mrow[r]) * rc;
      ebase[(size_t)r * Hn + colp] = f2bf(e);
    }
  }
}

// 4 WGs x 512 threads (8 waves). D = P(A) x alpha(B), sigma-permuted k-order.
// Lane (qg,l15) of wave w owns seq l15, cols {w*64 + mt*16 + qg*4 + r} — and packs
// those SAME 16 registers directly into its 16B BfI slot (no ut array, no transpose).
// BfI layout [slot16B][seq]: quantize write and MFMA read are both contiguous
// per-wave patterns (conflict-free).
__global__ __launch_bounds__(512, 2) void k_rec9(
    const ushort* __restrict__ eb, const float* __restrict__ rm,
    const u64* __restrict__ pq, const float* __restrict__ px0sp,
    const int* __restrict__ lens, float* __restrict__ outp) {
  const int grp = blockIdx.x;        // 0..3
  const int t = threadIdx.x;         // 0..511
  const int w = t >> 6;              // wave 0..7
  const int lane = t & 63, qg = lane >> 4, l15 = lane & 15;

  __shared__ uint4 BfI[32][16];      // alpha fp8 image [16B-slot][seq] (8 KB)
  __shared__ float sredM[16][12];    // per-seq per-wave partial max
  __shared__ float rmsL[16];
  __shared__ int lenl[16];

  // ---- persistent P fragments (A operand): wave w -> m-tiles 4w..4w+3 ----
  i32x8 PRv[16];
  {
    const uint4* pqv = (const uint4*)pq;
#pragma unroll
    for (int f = 0; f < 16; f++) {
      uint4 p0 = pqv[((size_t)(w * 16 + f) * 64 + lane) * 2 + 0];
      uint4 p1 = pqv[((size_t)(w * 16 + f) * 64 + lane) * 2 + 1];
      i32x8 v = {(int)p0.x, (int)p0.y, (int)p0.z, (int)p0.w,
                 (int)p1.x, (int)p1.y, (int)p1.z, (int)p1.w};
      PRv[f] = v;
    }
  }

  if (t < 16) lenl[t] = lens[grp * 16 + t];
  const size_t seqstride = (size_t)Tn * Hn;
  const ushort* myrow = eb + (size_t)(grp * 16 + l15) * seqstride + w * 64 + qg * 16;
  uint4* myslot = &BfI[w * 4 + qg][l15];

  float4 uv0, uv1, uv2, uv3;
  // ---- init: uv = px0sp * e' in the lane's natural (mt*4+r) order ----
  {
    uint4 e0 = *(const uint4*)myrow;
    uint4 e1 = *(const uint4*)(myrow + 8);
    float4 p0 = *(const float4*)(px0sp + w * 64 + qg * 16 + 0);
    float4 p1 = *(const float4*)(px0sp + w * 64 + qg * 16 + 4);
    float4 p2 = *(const float4*)(px0sp + w * 64 + qg * 16 + 8);
    float4 p3 = *(const float4*)(px0sp + w * 64 + qg * 16 + 12);
    uv0.x = p0.x * ubits(e0.x << 16);  uv0.y = p0.y * ubits(e0.x & 0xffff0000u);
    uv0.z = p0.z * ubits(e0.y << 16);  uv0.w = p0.w * ubits(e0.y & 0xffff0000u);
    uv1.x = p1.x * ubits(e0.z << 16);  uv1.y = p1.y * ubits(e0.z & 0xffff0000u);
    uv1.z = p1.z * ubits(e0.w << 16);  uv1.w = p1.w * ubits(e0.w & 0xffff0000u);
    uv2.x = p2.x * ubits(e1.x << 16);  uv2.y = p2.y * ubits(e1.x & 0xffff0000u);
    uv2.z = p2.z * ubits(e1.y << 16);  uv2.w = p2.w * ubits(e1.y & 0xffff0000u);
    uv3.x = p3.x * ubits(e1.z << 16);  uv3.y = p3.y * ubits(e1.z & 0xffff0000u);
    uv3.z = p3.z * ubits(e1.w << 16);  uv3.w = p3.w * ubits(e1.w & 0xffff0000u);
    float ma = max3f(max3f(uv0.x, uv0.y, uv0.z), max3f(uv0.w, uv1.x, uv1.y),
                     max3f(uv1.z, uv1.w, uv2.x));
    float mb = max3f(max3f(uv2.y, uv2.z, uv2.w), max3f(uv3.x, uv3.y, uv3.z), uv3.w);
    float mxv = fmaxf(ma, mb);
    mxv = fmaxf(mxv, __shfl_xor(mxv, 16, 64));
    mxv = fmaxf(mxv, __shfl_xor(mxv, 32, 64));
    if (qg == 0) sredM[l15][w] = mxv;
  }
  WG_BARRIER();
  const int t_end = lenl[15];
  const int lenq = lenl[l15];
  float L2acc;
  u64 myf0, myf1;

  // ---- step-0 quantize: pack OWN 16 registers into own slot ----
  {
    float4 g0 = *(const float4*)&sredM[l15][0];
    float4 g1 = *(const float4*)&sredM[l15][4];
    float gm = fmaxf(max3f(max3f(g0.x, g0.y, g0.z), max3f(g0.w, g1.x, g1.y), g1.z), g1.w);
    L2acc = __log2f(gm);
    float qs = 448.0f * __builtin_amdgcn_rcpf(gm);
    float v0[8] = {uv0.x, uv0.y, uv0.z, uv0.w, uv1.x, uv1.y, uv1.z, uv1.w};
    float v1[8] = {uv2.x, uv2.y, uv2.z, uv2.w, uv3.x, uv3.y, uv3.z, uv3.w};
    myf0 = pack8fp8(v0, qs);
    myf1 = pack8fp8(v1, qs);
    *myslot = (uint4){(uint)myf0, (uint)(myf0 >> 32), (uint)myf1, (uint)(myf1 >> 32)};
  }

  // ---- emit prefetch: one contiguous 32B per lane ----
  const ushort* epp = myrow + Hn;
  uint4 bpA = *(const uint4*)epp;
  uint4 bpB = *(const uint4*)(epp + 8);
  epp += Hn;

  // ---- recursion: 2 lgkm-only barriers/step ----
  for (int ts = 1; ts < t_end; ts++) {
    WG_BARRIER();  // BAR0: BfI published

    // hoist ALL 8 B-frag reads: 8 ds_read_b128 pipeline before the MFMA chain
    uint4 bfr[8];
#pragma unroll
    for (int s = 0; s < 8; s++) bfr[s] = BfI[(s >> 1) * 8 + qg * 2 + (s & 1)][l15];

    // MFMA: 4 k-blocks (K=128) x 4 m-tiles; A=P regs, B=alpha LDS
    f32x4 ac0 = {0.f, 0.f, 0.f, 0.f}, ac1 = {0.f, 0.f, 0.f, 0.f};
    f32x4 ac2 = {0.f, 0.f, 0.f, 0.f}, ac3 = {0.f, 0.f, 0.f, 0.f};
    __builtin_amdgcn_s_setprio(1);
#pragma unroll
    for (int kb = 0; kb < 4; kb++) {
      uint4 b0 = bfr[kb * 2 + 0];
      uint4 b1 = bfr[kb * 2 + 1];
      i32x8 bf = {(int)b0.x, (int)b0.y, (int)b0.z, (int)b0.w,
                  (int)b1.x, (int)b1.y, (int)b1.z, (int)b1.w};
      ac0 = __builtin_amdgcn_mfma_scale_f32_16x16x128_f8f6f4(
          PRv[kb * 4 + 0], bf, ac0, 0, 0, 0, 0x7F7F7F7F, 0, 0x7F7F7F7F);
      ac1 = __builtin_amdgcn_mfma_scale_f32_16x16x128_f8f6f4(
          PRv[kb * 4 + 1], bf, ac1, 0, 0, 0, 0x7F7F7F7F, 0, 0x7F7F7F7F);
      ac2 = __builtin_amdgcn_mfma_scale_f32_16x16x128_f8f6f4(
          PRv[kb * 4 + 2], bf, ac2, 0, 0, 0, 0x7F7F7F7F, 0, 0x7F7F7F7F);
      ac3 = __builtin_amdgcn_mfma_scale_f32_16x16x128_f8f6f4(
          PRv[kb * 4 + 3], bf, ac3, 0, 0, 0, 0x7F7F7F7F, 0, 0x7F7F7F7F);
    }
    __builtin_amdgcn_s_setprio(0);

    // prefetch emit(ts+1) AFTER the MFMA issue (off the pre-MFMA critical path)
    uint4 bqA = *(const uint4*)epp;
    uint4 bqB = *(const uint4*)(epp + 8);
    epp += Hn;

    // epilogue: u = acc * e' entirely in registers; per-seq max via max3 + 2 shfl
    {
      uv0.x = ac0[0] * ubits(bpA.x << 16);  uv0.y = ac0[1] * ubits(bpA.x & 0xffff0000u);
      uv0.z = ac0[2] * ubits(bpA.y << 16);  uv0.w = ac0[3] * ubits(bpA.y & 0xffff0000u);
      uv1.x = ac1[0] * ubits(bpA.z << 16);  uv1.y = ac1[1] * ubits(bpA.z & 0xffff0000u);
      uv1.z = ac1[2] * ubits(bpA.w << 16);  uv1.w = ac1[3] * ubits(bpA.w & 0xffff0000u);
      uv2.x = ac2[0] * ubits(bpB.x << 16);  uv2.y = ac2[1] * ubits(bpB.x & 0xffff0000u);
      uv2.z = ac2[2] * ubits(bpB.y << 16);  uv2.w = ac2[3] * ubits(bpB.y & 0xffff0000u);
      uv3.x = ac3[0] * ubits(bpB.z << 16);  uv3.y = ac3[1] * ubits(bpB.z & 0xffff0000u);
      uv3.z = ac3[2] * ubits(bpB.w << 16);  uv3.w = ac3[3] * ubits(bpB.w & 0xffff0000u);
      float ma = max3f(max3f(uv0.x, uv0.y, uv0.z), max3f(uv0.w, uv1.x, uv1.y),
                       max3f(uv1.z, uv1.w, uv2.x));
      float mb = max3f(max3f(uv2.y, uv2.z, uv2.w), max3f(uv3.x, uv3.y, uv3.z), uv3.w);
      float mxv = fmaxf(ma, mb);
      mxv = fmaxf(mxv, __shfl_xor(mxv, 16, 64));
      mxv = fmaxf(mxv, __shfl_xor(mxv, 32, 64));
      if (qg == 0) sredM[l15][w] = mxv;
    }
    WG_BARRIER();  // BAR1: sredM published (only cross-wave dependency)

    // quantize: pack OWN registers, write own slot (conflict-free contiguous write)
    if (ts < lenq) {
      float4 g0 = *(const float4*)&sredM[l15][0];
      float4 g1 = *(const float4*)&sredM[l15][4];
      float gm = fmaxf(max3f(max3f(g0.x, g0.y, g0.z), max3f(g0.w, g1.x, g1.y), g1.z), g1.w);
      L2acc += __log2f(gm);
      float qs = 448.0f * __builtin_amdgcn_rcpf(gm);
      float v0[8] = {uv0.x, uv0.y, uv0.z, uv0.w, uv1.x, uv1.y, uv1.z, uv1.w};
      float v1[8] = {uv2.x, uv2.y, uv2.z, uv2.w, uv3.x, uv3.y, uv3.z, uv3.w};
      myf0 = pack8fp8(v0, qs);
      myf1 = pack8fp8(v1, qs);
      *myslot = (uint4){(uint)myf0, (uint)(myf0 >> 32), (uint)myf1, (uint)(myf1 >> 32)};
    }
    bpA = bqA; bpB = bqB;
  }

  // ---- finale ----
  WG_BARRIER();
  {
    float ps = 0.f;
#pragma unroll
    for (int j = 0; j < 8; j++) {
      ps += fp8val((uint)(myf0 >> (8 * j)) & 0xffu);
      ps += fp8val((uint)(myf1 >> (8 * j)) & 0xffu);
    }
    ps += __shfl_xor(ps, 16, 64);
    ps += __shfl_xor(ps, 32, 64);
    if (qg == 0) sredM[l15][w] = ps;  // partial sum over this wave's k-window, seq l15
  }
  // rm sums: wave w handles seqs 2w (lanes 0..31), 2w+1 (lanes 32..63)
  {
    int sq = 2 * w + (lane >> 5), tl = lane & 31;
    const float* rp = rm + (size_t)(grp * 16 + sq) * Tn;
    int ls = lenl[sq];
    float rs = 0.f;
#pragma unroll
    for (int k = 0; k < 16; k++) {
      int idx = tl + 32 * k;
      float v = rp[idx];
      rs += (idx < ls) ? v : 0.f;
    }
#pragma unroll
    for (int o = 1; o < 32; o <<= 1) rs += __shfl_xor(rs, o, 64);
    if ((lane & 31) == 0) rmsL[sq] = rs;
  }
  __syncthreads();
  if (t < 16) {  // wave 0, qg 0, l15 = t: holds L2acc/lenq for seq t
    float4 s0 = *(const float4*)&sredM[t][0];
    float4 s1 = *(const float4*)&sredM[t][4];
    float Ss = (s0.x + s0.y) + (s0.z + s0.w) + (s1.x + s1.y) + (s1.z + s1.w);
    outp[grp * 16 + t] = 0.6931471805599453f * L2acc - (float)lenq * 6.104793232414985f
                         + logf(Ss) + rmsL[t];
  }
}

extern "C" void kernel_launch(void* const* d_in, const int* in_sizes, int n_in,
                              void* d_out, int out_size, void* d_ws, size_t ws_size,
                              hipStream_t stream) {
  const float* seq = (const float*)d_in[0];
  const int* lens = (const int*)d_in[1];
  const float* px = (const float*)d_in[2];
  const float* py = (const float*)d_in[3];
  char* ws = (char*)d_ws;
  ushort* emitb = (ushort*)(ws + 0x0000000);
  float* rm     = (float*)(ws + 0x2000000);
  ushort* wmatb = (ushort*)(ws + 0x2020000);
  float* bias   = (float*)(ws + 0x2060000);
  float* rcsg   = (float*)(ws + 0x2062000);
  float* px0sp  = (float*)(ws + 0x2063000);
  u64* pq       = (u64*)(ws + 0x2070000);
  float* outp   = (float*)d_out;

  hipLaunchKernelGGL(k_preppq, dim3(288), dim3(256), 0, stream, py, px, wmatb, bias, rcsg, px0sp, pq);
  hipLaunchKernelGGL(k_emit3, dim3(NT / 64), dim3(256), 0, stream, seq, wmatb, bias, rcsg, emitb, rm);
  hipLaunchKernelGGL(k_rec9, dim3(4), dim3(512), 0, stream, emitb, rm, pq, px0sp, lens, outp);
}